// Round 1
// baseline (1740.738 us; speedup 1.0000x reference)
//
#include <hip/hip_runtime.h>

#define NTOK   8192
#define DMODEL 1024
#define NATOM  16384

typedef _Float16 half8  __attribute__((ext_vector_type(8)));
typedef _Float16 half4_t __attribute__((ext_vector_type(4)));
typedef float    f32x4  __attribute__((ext_vector_type(4)));

// async global->LDS, 16B per lane; LDS dest is wave-uniform base + lane*16
#define GLOAD_LDS16(gsrc, ldst) \
  __builtin_amdgcn_global_load_lds((const __attribute__((address_space(1))) unsigned int*)(gsrc), \
                                   (__attribute__((address_space(3))) unsigned int*)(ldst), 16, 0, 0)

// ---------------- prep: fp32 -> fp16 ----------------
__global__ void cvt_f32_f16(const float* __restrict__ in, _Float16* __restrict__ out, int n4) {
  int i = blockIdx.x * 256 + threadIdx.x;
  if (i >= n4) return;
  float4 v = ((const float4*)in)[i];
  half4_t h;
  h[0] = (_Float16)v.x; h[1] = (_Float16)v.y; h[2] = (_Float16)v.z; h[3] = (_Float16)v.w;
  ((half4_t*)out)[i] = h;
}

// ---------------- prep: dict [16384,1024] f32 -> dT [1024,16384] f16 ----------------
__global__ void transpose_dict(const float* __restrict__ dict, _Float16* __restrict__ dT) {
  __shared__ _Float16 tile[64][68];
  int a0 = blockIdx.x * 64;   // atom tile
  int d0 = blockIdx.y * 64;   // dim tile
  int tid = threadIdx.x;
  int c = tid & 63;
  int r0 = tid >> 6;
  #pragma unroll
  for (int i = 0; i < 16; i++) {
    int r = r0 + i * 4;
    tile[r][c] = (_Float16)dict[(size_t)(a0 + r) * DMODEL + d0 + c];
  }
  __syncthreads();
  #pragma unroll
  for (int i = 0; i < 16; i++) {
    int rd = r0 + i * 4;
    dT[(size_t)(d0 + rd) * NATOM + a0 + c] = tile[c][rd];
  }
}

// ---------------- kernel 1: E = mask ? exp(x @ dict^T) : 0  (fp16 out) ----------------
// 128x128 tile, BK=32, 4 waves (2x2), mfma_f32_16x16x32_f16. NT layout: both operands K-contig.
__launch_bounds__(256, 2)
__global__ void score_kernel(const _Float16* __restrict__ Xh,
                             const _Float16* __restrict__ Dh,
                             const int* __restrict__ mask,
                             _Float16* __restrict__ E) {
  __shared__ _Float16 lds[17408];          // staging 16KB; epilogue 128x(stride 136) = 34KB
  _Float16* As = lds;
  _Float16* Bs = lds + 4096;
  const int tid  = threadIdx.x;
  const int lane = tid & 63;
  const int wave = tid >> 6;
  const int wm = wave >> 1, wn = wave & 1;
  const int m0 = blockIdx.y * 128;         // token tile
  const int n0 = blockIdx.x * 128;         // atom tile

  const int srow = tid >> 2;               // staging row 0..63
  const int scol = (tid & 3) * 8;          // staging k-chunk
  const int frow = lane & 15;              // fragment row
  const int fk   = (lane >> 4) * 8;        // fragment k offset

  f32x4 acc[4][4] = {};

  for (int k0 = 0; k0 < DMODEL; k0 += 32) {
    __syncthreads();
    GLOAD_LDS16(Xh + (size_t)(m0 + srow) * DMODEL + k0 + scol,      As + (size_t)tid * 8);
    GLOAD_LDS16(Xh + (size_t)(m0 + 64 + srow) * DMODEL + k0 + scol, As + 2048 + (size_t)tid * 8);
    GLOAD_LDS16(Dh + (size_t)(n0 + srow) * DMODEL + k0 + scol,      Bs + (size_t)tid * 8);
    GLOAD_LDS16(Dh + (size_t)(n0 + 64 + srow) * DMODEL + k0 + scol, Bs + 2048 + (size_t)tid * 8);
    __syncthreads();
    half8 af[4], bf[4];
    #pragma unroll
    for (int i = 0; i < 4; i++) {
      af[i] = *(const half8*)&As[(wm * 64 + i * 16 + frow) * 32 + fk];
      bf[i] = *(const half8*)&Bs[(wn * 64 + i * 16 + frow) * 32 + fk];
    }
    #pragma unroll
    for (int i = 0; i < 4; i++)
      #pragma unroll
      for (int j = 0; j < 4; j++)
        acc[i][j] = __builtin_amdgcn_mfma_f32_16x16x32_f16(af[i], bf[j], acc[i][j], 0, 0, 0);
  }

  __syncthreads();
  // epilogue: C/D layout col=lane&15, row=(lane>>4)*4+reg. mask+exp -> LDS (stride 136 = bank-spread,
  // 272B rows are 16B-aligned) -> coalesced fp16 store.
  const int cr = (lane >> 4) * 4;
  const int cc = lane & 15;
  #pragma unroll
  for (int i = 0; i < 4; i++) {
    #pragma unroll
    for (int j = 0; j < 4; j++) {
      #pragma unroll
      for (int r = 0; r < 4; r++) {
        int lr = wm * 64 + i * 16 + cr + r;
        int lc = wn * 64 + j * 16 + cc;
        int mk = mask[(size_t)(m0 + lr) * NATOM + (n0 + lc)];
        float e = mk ? __expf(acc[i][j][r]) : 0.0f;   // scores bounded |s|<=11: no max-subtract needed
        lds[lr * 136 + lc] = (_Float16)e;
      }
    }
  }
  __syncthreads();
  #pragma unroll
  for (int i = 0; i < 8; i++) {
    int chunk = i * 256 + tid;
    int r  = chunk >> 4;
    int c8 = (chunk & 15) * 8;
    *(half8*)&E[(size_t)(m0 + r) * NATOM + n0 + c8] = *(const half8*)&lds[r * 136 + c8];
  }
}

// ---------------- kernel 2: row sums l, candidates, exact fp64 argmax ----------------
__global__ void scan_kernel(const _Float16* __restrict__ E,
                            const float* __restrict__ x,
                            const float* __restrict__ dict,
                            float* __restrict__ lsum,
                            float* __restrict__ argout) {
  const int t = blockIdx.x;
  const int tid = threadIdx.x;
  const int lane = tid & 63;
  const int wid = tid >> 6;
  const _Float16* row = E + (size_t)t * NATOM;

  half8 v[8];                               // keep the row slice in regs (32 VGPRs)
  float mx = 0.0f, sm = 0.0f;
  #pragma unroll
  for (int i = 0; i < 8; i++) {
    v[i] = *(const half8*)&row[i * 2048 + tid * 8];
    #pragma unroll
    for (int j = 0; j < 8; j++) {
      float f = (float)v[i][j];
      sm += f;
      mx = fmaxf(mx, f);
    }
  }
  #pragma unroll
  for (int off = 32; off > 0; off >>= 1) {
    mx = fmaxf(mx, __shfl_down(mx, off, 64));
    sm += __shfl_down(sm, off, 64);
  }
  __shared__ float wmx[4], wsm[4];
  __shared__ float bmax, bsum;
  __shared__ int cnt;
  __shared__ int cand[64];
  __shared__ double csc[64];
  __shared__ double dred[4];
  if (lane == 0) { wmx[wid] = mx; wsm[wid] = sm; }
  if (tid == 0) cnt = 0;
  __syncthreads();
  if (tid == 0) {
    bmax = fmaxf(fmaxf(wmx[0], wmx[1]), fmaxf(wmx[2], wmx[3]));
    bsum = wsm[0] + wsm[1] + wsm[2] + wsm[3];
  }
  __syncthreads();
  float thr = bmax * 0.98f;   // margin ln(1/0.98)=0.020 in score units ~ 84 sigma of fp16-GEMM error
  if (bmax > 0.0f) {
    #pragma unroll
    for (int i = 0; i < 8; i++) {
      #pragma unroll
      for (int j = 0; j < 8; j++) {
        if ((float)v[i][j] >= thr) {
          int p = atomicAdd(&cnt, 1);
          if (p < 64) cand[p] = i * 2048 + tid * 8 + j;
        }
      }
    }
  }
  __syncthreads();
  int nc = min(cnt, 64);
  for (int c = 0; c < nc; c++) {
    const float* dr = dict + (size_t)cand[c] * DMODEL;
    const float* xr = x + (size_t)t * DMODEL;
    double a = 0.0;
    for (int d = tid; d < DMODEL; d += 256)
      a += (double)xr[d] * (double)dr[d];
    #pragma unroll
    for (int off = 32; off > 0; off >>= 1)
      a += __shfl_down(a, off, 64);
    if (lane == 0) dred[wid] = a;
    __syncthreads();
    if (tid == 0) csc[c] = dred[0] + dred[1] + dred[2] + dred[3];
    __syncthreads();
  }
  if (tid == 0) {
    lsum[t] = bsum;
    int best = 0;                           // all-masked -> np.argmax of equal values = 0
    if (nc > 0) {
      double bs = -1e300;
      best = NATOM;
      for (int c = 0; c < nc; c++) {
        if (csc[c] > bs || (csc[c] == bs && cand[c] < best)) { bs = csc[c]; best = cand[c]; }
      }
    }
    argout[t] = (float)best;                // harness reads d_out as float32
  }
}

// ---------------- kernel 3: recon = (E @ dT^T) / l ----------------
__launch_bounds__(256, 2)
__global__ void recon_kernel(const _Float16* __restrict__ E,
                             const _Float16* __restrict__ DT,
                             const float* __restrict__ lsum,
                             float* __restrict__ out) {
  __shared__ _Float16 lds[8192];
  _Float16* As = lds;
  _Float16* Bs = lds + 4096;
  const int tid  = threadIdx.x;
  const int lane = tid & 63;
  const int wave = tid >> 6;
  const int wm = wave >> 1, wn = wave & 1;
  const int m0 = blockIdx.y * 128;         // token tile
  const int n0 = blockIdx.x * 128;         // d_model tile (8 tiles)

  const int srow = tid >> 2;
  const int scol = (tid & 3) * 8;
  const int frow = lane & 15;
  const int fk   = (lane >> 4) * 8;

  f32x4 acc[4][4] = {};

  for (int k0 = 0; k0 < NATOM; k0 += 32) {
    __syncthreads();
    GLOAD_LDS16(E  + (size_t)(m0 + srow) * NATOM + k0 + scol,      As + (size_t)tid * 8);
    GLOAD_LDS16(E  + (size_t)(m0 + 64 + srow) * NATOM + k0 + scol, As + 2048 + (size_t)tid * 8);
    GLOAD_LDS16(DT + (size_t)(n0 + srow) * NATOM + k0 + scol,      Bs + (size_t)tid * 8);
    GLOAD_LDS16(DT + (size_t)(n0 + 64 + srow) * NATOM + k0 + scol, Bs + 2048 + (size_t)tid * 8);
    __syncthreads();
    half8 af[4], bf[4];
    #pragma unroll
    for (int i = 0; i < 4; i++) {
      af[i] = *(const half8*)&As[(wm * 64 + i * 16 + frow) * 32 + fk];
      bf[i] = *(const half8*)&Bs[(wn * 64 + i * 16 + frow) * 32 + fk];
    }
    #pragma unroll
    for (int i = 0; i < 4; i++)
      #pragma unroll
      for (int j = 0; j < 4; j++)
        acc[i][j] = __builtin_amdgcn_mfma_f32_16x16x32_f16(af[i], bf[j], acc[i][j], 0, 0, 0);
  }

  const int cr = (lane >> 4) * 4;
  const int cc = lane & 15;
  #pragma unroll
  for (int i = 0; i < 4; i++) {
    #pragma unroll
    for (int r = 0; r < 4; r++) {
      int lr = wm * 64 + i * 16 + cr + r;
      float sc = 1.0f / lsum[m0 + lr];
      #pragma unroll
      for (int j = 0; j < 4; j++) {
        int lc = wn * 64 + j * 16 + cc;
        out[(size_t)(m0 + lr) * DMODEL + (n0 + lc)] = acc[i][j][r] * sc;
      }
    }
  }
}

extern "C" void kernel_launch(void* const* d_in, const int* in_sizes, int n_in,
                              void* d_out, int out_size, void* d_ws, size_t ws_size,
                              hipStream_t stream) {
  const float* x    = (const float*)d_in[0];
  const float* dict = (const float*)d_in[1];
  const int*   mask = (const int*)d_in[2];
  float* recon  = (float*)d_out;
  float* argout = recon + (size_t)NTOK * DMODEL;

  // workspace layout (needs 336 MB + 32 KB)
  char* w = (char*)d_ws;
  _Float16* Xh = (_Float16*)(w);                                 // 16 MB  [8192,1024]
  _Float16* Dh = (_Float16*)(w + (size_t)16  * 1024 * 1024);     // 32 MB  [16384,1024]
  _Float16* DT = (_Float16*)(w + (size_t)48  * 1024 * 1024);     // 32 MB  [1024,16384]
  _Float16* E  = (_Float16*)(w + (size_t)80  * 1024 * 1024);     // 256 MB [8192,16384]
  float*  lsum = (float*)  (w + (size_t)336 * 1024 * 1024);      // 32 KB

  cvt_f32_f16<<<dim3(NTOK * DMODEL / 4 / 256), 256, 0, stream>>>(x, Xh, NTOK * DMODEL / 4);
  cvt_f32_f16<<<dim3(NATOM * DMODEL / 4 / 256), 256, 0, stream>>>(dict, Dh, NATOM * DMODEL / 4);
  transpose_dict<<<dim3(NATOM / 64, DMODEL / 64), 256, 0, stream>>>(dict, DT);
  score_kernel<<<dim3(NATOM / 128, NTOK / 128), 256, 0, stream>>>(Xh, Dh, mask, E);
  scan_kernel<<<dim3(NTOK), 256, 0, stream>>>(E, x, dict, lsum, argout);
  recon_kernel<<<dim3(DMODEL / 128, NTOK / 128), 256, 0, stream>>>(E, DT, lsum, recon);
}

// Round 2
// 1656.355 us; speedup vs baseline: 1.0509x; 1.0509x over previous
//
#include <hip/hip_runtime.h>

#define NTOK   8192
#define DMODEL 1024
#define NATOM  16384

typedef _Float16 half8  __attribute__((ext_vector_type(8)));
typedef _Float16 half4_t __attribute__((ext_vector_type(4)));
typedef float    f32x4  __attribute__((ext_vector_type(4)));

// async global->LDS, 16B per lane; LDS dest is wave-uniform base + lane*16
#define GLOAD_LDS16(gsrc, ldst) \
  __builtin_amdgcn_global_load_lds((const __attribute__((address_space(1))) unsigned int*)(gsrc), \
                                   (__attribute__((address_space(3))) unsigned int*)(ldst), 16, 0, 0)

// ---------------- prep: fp32 -> fp16 ----------------
__global__ void cvt_f32_f16(const float* __restrict__ in, _Float16* __restrict__ out, int n4) {
  int i = blockIdx.x * 256 + threadIdx.x;
  if (i >= n4) return;
  float4 v = ((const float4*)in)[i];
  half4_t h;
  h[0] = (_Float16)v.x; h[1] = (_Float16)v.y; h[2] = (_Float16)v.z; h[3] = (_Float16)v.w;
  ((half4_t*)out)[i] = h;
}

// ---------------- prep: dict [16384,1024] f32 -> dT [1024,16384] f16 ----------------
__global__ void transpose_dict(const float* __restrict__ dict, _Float16* __restrict__ dT) {
  __shared__ _Float16 tile[64][68];
  int a0 = blockIdx.x * 64;   // atom tile
  int d0 = blockIdx.y * 64;   // dim tile
  int tid = threadIdx.x;
  int c = tid & 63;
  int r0 = tid >> 6;
  #pragma unroll
  for (int i = 0; i < 16; i++) {
    int r = r0 + i * 4;
    tile[r][c] = (_Float16)dict[(size_t)(a0 + r) * DMODEL + d0 + c];
  }
  __syncthreads();
  #pragma unroll
  for (int i = 0; i < 16; i++) {
    int rd = r0 + i * 4;
    dT[(size_t)(d0 + rd) * NATOM + a0 + c] = tile[c][rd];
  }
}

// ---------------- kernel 1: E = mask ? exp(x @ dict^T) : 0  (fp16 out) ----------------
// 128x128 tile, BK=32, 4 waves (2x2), mfma_f32_16x16x32_f16. NT layout: both operands K-contig.
// LDS k-chunk XOR-swizzle (on the global SOURCE side, since global_load_lds dest is lane-fixed):
// physical chunk pc of row r holds logical chunk pc ^ ((r>>1)&3) -> fragment b128 reads spread
// over all 32 banks (max 2-way aliasing = free) instead of 8-way conflicts.
__launch_bounds__(256, 2)
__global__ void score_kernel(const _Float16* __restrict__ Xh,
                             const _Float16* __restrict__ Dh,
                             const int* __restrict__ mask,
                             _Float16* __restrict__ E) {
  __shared__ _Float16 lds[17408];          // staging 16KB; epilogue 128x(stride 136) = 34KB
  _Float16* As = lds;
  _Float16* Bs = lds + 4096;
  const int tid  = threadIdx.x;
  const int lane = tid & 63;
  const int wave = tid >> 6;
  const int wm = wave >> 1, wn = wave & 1;
  const int m0 = blockIdx.y * 128;         // token tile
  const int n0 = blockIdx.x * 128;         // atom tile

  const int frow = lane & 15;              // fragment row
  const int fkc  = lane >> 4;              // fragment k-chunk (0..3)

  f32x4 acc[4][4] = {};

  for (int k0 = 0; k0 < DMODEL; k0 += 32) {
    __syncthreads();
    #pragma unroll
    for (int i = 0; i < 2; i++) {
      int L = tid + i * 256;               // 0..511 covers 128 rows x 4 chunks
      int r = L >> 2, pc = L & 3;
      int c = pc ^ ((r >> 1) & 3);         // swizzled source chunk
      GLOAD_LDS16(Xh + (size_t)(m0 + r) * DMODEL + k0 + c * 8, As + (size_t)L * 8);
      GLOAD_LDS16(Dh + (size_t)(n0 + r) * DMODEL + k0 + c * 8, Bs + (size_t)L * 8);
    }
    __syncthreads();
    half8 af[4], bf[4];
    #pragma unroll
    for (int i = 0; i < 4; i++) {
      int ar = wm * 64 + i * 16 + frow;
      int br = wn * 64 + i * 16 + frow;
      af[i] = *(const half8*)&As[ar * 32 + (fkc ^ ((ar >> 1) & 3)) * 8];
      bf[i] = *(const half8*)&Bs[br * 32 + (fkc ^ ((br >> 1) & 3)) * 8];
    }
    #pragma unroll
    for (int i = 0; i < 4; i++)
      #pragma unroll
      for (int j = 0; j < 4; j++)
        acc[i][j] = __builtin_amdgcn_mfma_f32_16x16x32_f16(af[i], bf[j], acc[i][j], 0, 0, 0);
  }

  __syncthreads();
  // epilogue: C/D layout col=lane&15, row=(lane>>4)*4+reg. mask+exp -> LDS (stride 136 = bank-spread,
  // 272B rows are 16B-aligned) -> coalesced fp16 store.
  const int cr = (lane >> 4) * 4;
  const int cc = lane & 15;
  #pragma unroll
  for (int i = 0; i < 4; i++) {
    #pragma unroll
    for (int j = 0; j < 4; j++) {
      #pragma unroll
      for (int r = 0; r < 4; r++) {
        int lr = wm * 64 + i * 16 + cr + r;
        int lc = wn * 64 + j * 16 + cc;
        int mk = mask[(size_t)(m0 + lr) * NATOM + (n0 + lc)];
        float e = mk ? __expf(acc[i][j][r]) : 0.0f;   // scores bounded |s|<=11: no max-subtract needed
        lds[lr * 136 + lc] = (_Float16)e;
      }
    }
  }
  __syncthreads();
  #pragma unroll
  for (int i = 0; i < 8; i++) {
    int chunk = i * 256 + tid;
    int r  = chunk >> 4;
    int c8 = (chunk & 15) * 8;
    *(half8*)&E[(size_t)(m0 + r) * NATOM + n0 + c8] = *(const half8*)&lds[r * 136 + c8];
  }
}

// ---------------- kernel 2: row sums l, candidates, exact fp64 argmax ----------------
__global__ void scan_kernel(const _Float16* __restrict__ E,
                            const float* __restrict__ x,
                            const float* __restrict__ dict,
                            float* __restrict__ lsum,
                            float* __restrict__ argout) {
  const int t = blockIdx.x;
  const int tid = threadIdx.x;
  const int lane = tid & 63;
  const int wid = tid >> 6;
  const _Float16* row = E + (size_t)t * NATOM;

  half8 v[8];                               // keep the row slice in regs (32 VGPRs)
  float mx = 0.0f, sm = 0.0f;
  #pragma unroll
  for (int i = 0; i < 8; i++) {
    v[i] = *(const half8*)&row[i * 2048 + tid * 8];
    #pragma unroll
    for (int j = 0; j < 8; j++) {
      float f = (float)v[i][j];
      sm += f;
      mx = fmaxf(mx, f);
    }
  }
  #pragma unroll
  for (int off = 32; off > 0; off >>= 1) {
    mx = fmaxf(mx, __shfl_down(mx, off, 64));
    sm += __shfl_down(sm, off, 64);
  }
  __shared__ float wmx[4], wsm[4];
  __shared__ float bmax, bsum;
  __shared__ int cnt;
  __shared__ int cand[64];
  __shared__ double csc[64];
  __shared__ double dred[4];
  if (lane == 0) { wmx[wid] = mx; wsm[wid] = sm; }
  if (tid == 0) cnt = 0;
  __syncthreads();
  if (tid == 0) {
    bmax = fmaxf(fmaxf(wmx[0], wmx[1]), fmaxf(wmx[2], wmx[3]));
    bsum = wsm[0] + wsm[1] + wsm[2] + wsm[3];
  }
  __syncthreads();
  float thr = bmax * 0.98f;   // margin ln(1/0.98)=0.020 in score units ~ 84 sigma of fp16-GEMM error
  if (bmax > 0.0f) {
    #pragma unroll
    for (int i = 0; i < 8; i++) {
      #pragma unroll
      for (int j = 0; j < 8; j++) {
        if ((float)v[i][j] >= thr) {
          int p = atomicAdd(&cnt, 1);
          if (p < 64) cand[p] = i * 2048 + tid * 8 + j;
        }
      }
    }
  }
  __syncthreads();
  int nc = min(cnt, 64);
  for (int c = 0; c < nc; c++) {
    const float* dr = dict + (size_t)cand[c] * DMODEL;
    const float* xr = x + (size_t)t * DMODEL;
    double a = 0.0;
    for (int d = tid; d < DMODEL; d += 256)
      a += (double)xr[d] * (double)dr[d];
    #pragma unroll
    for (int off = 32; off > 0; off >>= 1)
      a += __shfl_down(a, off, 64);
    if (lane == 0) dred[wid] = a;
    __syncthreads();
    if (tid == 0) csc[c] = dred[0] + dred[1] + dred[2] + dred[3];
    __syncthreads();
  }
  if (tid == 0) {
    lsum[t] = bsum;
    int best = 0;                           // all-masked -> np.argmax of equal values = 0
    if (nc > 0) {
      double bs = -1e300;
      best = NATOM;
      for (int c = 0; c < nc; c++) {
        if (csc[c] > bs || (csc[c] == bs && cand[c] < best)) { bs = csc[c]; best = cand[c]; }
      }
    }
    argout[t] = (float)best;                // harness reads d_out as float32
  }
}

// ---------------- kernel 3: recon = (E @ dT^T) / l ----------------
// Retiled vs round 1: M64 x N256, grid (4,128)=512 blocks (2/CU). E HBM traffic drops
// 8x -> 4x nominal (and the 4 consecutive n-blocks per m-tile share the E slice via LLC).
// 4 waves, each a 64x64 tile = 4x4 fragments (32 FLOP per LDS byte, same as score).
__launch_bounds__(256, 2)
__global__ void recon_kernel(const _Float16* __restrict__ E,
                             const _Float16* __restrict__ DT,
                             const float* __restrict__ lsum,
                             float* __restrict__ out) {
  __shared__ _Float16 lds[10240];          // As 64x32 (4KB) + Bs 256x32 (16KB)
  _Float16* As = lds;
  _Float16* Bs = lds + 2048;
  const int tid  = threadIdx.x;
  const int lane = tid & 63;
  const int wave = tid >> 6;               // n-offset = wave*64
  const int m0 = blockIdx.y * 64;          // token tile
  const int n0 = blockIdx.x * 256;         // d_model tile (4 tiles)

  const int frow = lane & 15;
  const int fkc  = lane >> 4;

  f32x4 acc[4][4] = {};

  for (int k0 = 0; k0 < NATOM; k0 += 32) {
    __syncthreads();
    {
      int L = tid;                         // 256 lanes = 64 rows x 4 chunks
      int r = L >> 2, pc = L & 3;
      int c = pc ^ ((r >> 1) & 3);
      GLOAD_LDS16(E + (size_t)(m0 + r) * NATOM + k0 + c * 8, As + (size_t)L * 8);
    }
    #pragma unroll
    for (int i = 0; i < 4; i++) {
      int L = tid + i * 256;               // 1024 lanes = 256 rows x 4 chunks
      int r = L >> 2, pc = L & 3;
      int c = pc ^ ((r >> 1) & 3);
      GLOAD_LDS16(DT + (size_t)(n0 + r) * NATOM + k0 + c * 8, Bs + (size_t)L * 8);
    }
    __syncthreads();
    half8 af[4], bf[4];
    #pragma unroll
    for (int i = 0; i < 4; i++) {
      int ar = i * 16 + frow;
      int br = wave * 64 + i * 16 + frow;
      af[i] = *(const half8*)&As[ar * 32 + (fkc ^ ((ar >> 1) & 3)) * 8];
      bf[i] = *(const half8*)&Bs[br * 32 + (fkc ^ ((br >> 1) & 3)) * 8];
    }
    #pragma unroll
    for (int i = 0; i < 4; i++)
      #pragma unroll
      for (int j = 0; j < 4; j++)
        acc[i][j] = __builtin_amdgcn_mfma_f32_16x16x32_f16(af[i], bf[j], acc[i][j], 0, 0, 0);
  }

  const int cr = (lane >> 4) * 4;
  const int cc = lane & 15;
  #pragma unroll
  for (int i = 0; i < 4; i++) {
    #pragma unroll
    for (int r = 0; r < 4; r++) {
      int lr = i * 16 + cr + r;
      float sc = 1.0f / lsum[m0 + lr];
      #pragma unroll
      for (int j = 0; j < 4; j++) {
        int lc = wave * 64 + j * 16 + cc;
        out[(size_t)(m0 + lr) * DMODEL + (n0 + lc)] = acc[i][j][r] * sc;
      }
    }
  }
}

extern "C" void kernel_launch(void* const* d_in, const int* in_sizes, int n_in,
                              void* d_out, int out_size, void* d_ws, size_t ws_size,
                              hipStream_t stream) {
  const float* x    = (const float*)d_in[0];
  const float* dict = (const float*)d_in[1];
  const int*   mask = (const int*)d_in[2];
  float* recon  = (float*)d_out;
  float* argout = recon + (size_t)NTOK * DMODEL;

  // workspace layout (needs 336 MB + 32 KB)
  char* w = (char*)d_ws;
  _Float16* Xh = (_Float16*)(w);                                 // 16 MB  [8192,1024]
  _Float16* Dh = (_Float16*)(w + (size_t)16  * 1024 * 1024);     // 32 MB  [16384,1024]
  _Float16* DT = (_Float16*)(w + (size_t)48  * 1024 * 1024);     // 32 MB  [1024,16384]
  _Float16* E  = (_Float16*)(w + (size_t)80  * 1024 * 1024);     // 256 MB [8192,16384]
  float*  lsum = (float*)  (w + (size_t)336 * 1024 * 1024);      // 32 KB

  cvt_f32_f16<<<dim3(NTOK * DMODEL / 4 / 256), 256, 0, stream>>>(x, Xh, NTOK * DMODEL / 4);
  cvt_f32_f16<<<dim3(NATOM * DMODEL / 4 / 256), 256, 0, stream>>>(dict, Dh, NATOM * DMODEL / 4);
  transpose_dict<<<dim3(NATOM / 64, DMODEL / 64), 256, 0, stream>>>(dict, DT);
  score_kernel<<<dim3(NATOM / 128, NTOK / 128), 256, 0, stream>>>(Xh, Dh, mask, E);
  scan_kernel<<<dim3(NTOK), 256, 0, stream>>>(E, x, dict, lsum, argout);
  recon_kernel<<<dim3(DMODEL / 256, NTOK / 64), 256, 0, stream>>>(E, DT, lsum, recon);
}

// Round 3
// 1494.458 us; speedup vs baseline: 1.1648x; 1.1083x over previous
//
#include <hip/hip_runtime.h>

#define NTOK   8192
#define DMODEL 1024
#define NATOM  16384

typedef _Float16 half8  __attribute__((ext_vector_type(8)));
typedef _Float16 half4_t __attribute__((ext_vector_type(4)));
typedef float    f32x4  __attribute__((ext_vector_type(4)));

// async global->LDS, 16B per lane; LDS dest is wave-uniform base + lane*16
#define GLOAD_LDS16(gsrc, ldst) \
  __builtin_amdgcn_global_load_lds((const __attribute__((address_space(1))) unsigned int*)(gsrc), \
                                   (__attribute__((address_space(3))) unsigned int*)(ldst), 16, 0, 0)

// ---------------- prep: fp32 -> fp16 (x only) ----------------
__global__ void cvt_f32_f16(const float* __restrict__ in, _Float16* __restrict__ out, int n4) {
  int i = blockIdx.x * 256 + threadIdx.x;
  if (i >= n4) return;
  float4 v = ((const float4*)in)[i];
  half4_t h;
  h[0] = (_Float16)v.x; h[1] = (_Float16)v.y; h[2] = (_Float16)v.z; h[3] = (_Float16)v.w;
  ((half4_t*)out)[i] = h;
}

// ---------------- prep: dict f32 -> Dh [16384,1024] f16 AND dT [1024,16384] f16 ----------------
__global__ void transpose_dict(const float* __restrict__ dict,
                               _Float16* __restrict__ Dh, _Float16* __restrict__ dT) {
  __shared__ _Float16 tile[64][68];
  int a0 = blockIdx.x * 64;   // atom tile
  int d0 = blockIdx.y * 64;   // dim tile
  int tid = threadIdx.x;
  int c = tid & 63;
  int r0 = tid >> 6;
  #pragma unroll
  for (int i = 0; i < 16; i++) {
    int r = r0 + i * 4;
    _Float16 h = (_Float16)dict[(size_t)(a0 + r) * DMODEL + d0 + c];
    tile[r][c] = h;
    Dh[(size_t)(a0 + r) * DMODEL + d0 + c] = h;
  }
  __syncthreads();
  #pragma unroll
  for (int i = 0; i < 16; i++) {
    int rd = r0 + i * 4;
    dT[(size_t)(d0 + rd) * NATOM + a0 + c] = tile[c][rd];
  }
}

__global__ void zero_lsum(float* __restrict__ lsum) {
  lsum[blockIdx.x * 256 + threadIdx.x] = 0.0f;
}

// staging helper: 128 rows x 32 k, XOR k-chunk swizzle on the global source side
__device__ __forceinline__ void stage_ab(const _Float16* __restrict__ A,
                                         const _Float16* __restrict__ B,
                                         _Float16* As, _Float16* Bs,
                                         size_t arow0, size_t brow0, size_t ldk,
                                         int k0, int tid) {
  #pragma unroll
  for (int i = 0; i < 2; i++) {
    int L = tid + i * 256;               // 0..511 = 128 rows x 4 chunks
    int r = L >> 2, pc = L & 3;
    int c = pc ^ ((r >> 1) & 3);
    GLOAD_LDS16(A + (arow0 + r) * ldk + k0 + c * 8, As + (size_t)L * 8);
    GLOAD_LDS16(B + (brow0 + r) * ldk + k0 + c * 8, Bs + (size_t)L * 8);
  }
}

// ---------------- kernel 1: E = mask ? exp(x @ dict^T) : 0, + row-tile sum/max ----------------
// 128x128 tile, BK=32, double-buffered staging (2x16KB), 4 waves (2x2), mfma_f32_16x16x32_f16.
__launch_bounds__(256, 2)
__global__ void score_kernel(const _Float16* __restrict__ Xh,
                             const _Float16* __restrict__ Dh,
                             const int* __restrict__ mask,
                             _Float16* __restrict__ E,
                             float* __restrict__ lsum,
                             _Float16* __restrict__ Tmax) {   // [128 tiles][8192 tokens]
  __shared__ _Float16 lds[17408];          // dbuf staging 2x(As 4096 + Bs 4096); epilogue 128x136
  const int tid  = threadIdx.x;
  const int lane = tid & 63;
  const int wave = tid >> 6;
  const int wm = wave >> 1, wn = wave & 1;
  const int m0 = blockIdx.y * 128;         // token tile
  const int n0 = blockIdx.x * 128;         // atom tile

  const int frow = lane & 15;
  const int fkc  = lane >> 4;

  f32x4 acc[4][4] = {};

  stage_ab(Xh, Dh, lds, lds + 4096, m0, n0, DMODEL, 0, tid);
  int cur = 0;
  for (int it = 0; it < DMODEL / 32; ++it) {
    __syncthreads();                       // drains vmcnt: buf[cur] ready (issued 1 compute ago)
    if (it + 1 < DMODEL / 32)
      stage_ab(Xh, Dh, lds + (cur ^ 1) * 8192, lds + (cur ^ 1) * 8192 + 4096,
               m0, n0, DMODEL, (it + 1) * 32, tid);
    _Float16* As = lds + cur * 8192;
    _Float16* Bs = As + 4096;
    half8 af[4], bf[4];
    #pragma unroll
    for (int i = 0; i < 4; i++) {
      int ar = wm * 64 + i * 16 + frow;
      int br = wn * 64 + i * 16 + frow;
      af[i] = *(const half8*)&As[ar * 32 + (fkc ^ ((ar >> 1) & 3)) * 8];
      bf[i] = *(const half8*)&Bs[br * 32 + (fkc ^ ((br >> 1) & 3)) * 8];
    }
    #pragma unroll
    for (int i = 0; i < 4; i++)
      #pragma unroll
      for (int j = 0; j < 4; j++)
        acc[i][j] = __builtin_amdgcn_mfma_f32_16x16x32_f16(af[i], bf[j], acc[i][j], 0, 0, 0);
    cur ^= 1;
  }

  __syncthreads();
  // epilogue: C/D layout col=lane&15, row=(lane>>4)*4+reg. mask+exp -> LDS (stride 136) -> stores.
  const int cr = (lane >> 4) * 4;
  const int cc = lane & 15;
  #pragma unroll
  for (int i = 0; i < 4; i++) {
    #pragma unroll
    for (int j = 0; j < 4; j++) {
      #pragma unroll
      for (int r = 0; r < 4; r++) {
        int lr = wm * 64 + i * 16 + cr + r;
        int lc = wn * 64 + j * 16 + cc;
        int mk = mask[(size_t)(m0 + lr) * NATOM + (n0 + lc)];
        float e = mk ? __expf(acc[i][j][r]) : 0.0f;   // scores bounded |s|<=11: no max-subtract
        lds[lr * 136 + lc] = (_Float16)e;
      }
    }
  }
  __syncthreads();
  // coalesced E store
  #pragma unroll
  for (int i = 0; i < 8; i++) {
    int chunk = i * 256 + tid;
    int r  = chunk >> 4;
    int c8 = (chunk & 15) * 8;
    *(half8*)&E[(size_t)(m0 + r) * NATOM + n0 + c8] = *(const half8*)&lds[r * 136 + c8];
  }
  // per-row partial sum (-> atomic lsum) and tile max (-> Tmax, tile-major for coalesced store)
  {
    int r = tid >> 1, h = tid & 1;
    const _Float16* rowp = &lds[r * 136 + h * 64];
    float s = 0.0f, m = 0.0f;
    #pragma unroll
    for (int i = 0; i < 8; i++) {
      half8 v = *(const half8*)&rowp[i * 8];
      #pragma unroll
      for (int j = 0; j < 8; j++) { float f = (float)v[j]; s += f; m = fmaxf(m, f); }
    }
    s += __shfl_xor(s, 1, 64);
    m = fmaxf(m, __shfl_xor(m, 1, 64));
    if (h == 0) {
      atomicAdd(&lsum[m0 + r], s);
      Tmax[(size_t)blockIdx.x * NTOK + m0 + r] = (_Float16)m;
    }
  }
}

// ---------------- kernel 2: sparse argmax scan (1 wave / token) ----------------
// Reads 128 tile-maxes; only tiles with max >= 0.98*gmax get their 128 E values re-read.
// Any true-winner candidate satisfies e >= 0.98*tile_max >= 0.98*gmax margin (84 sigma of
// fp16-GEMM error), then exact fp64 re-evaluation, ties -> lowest index (np.argmax).
__global__ void scan_lite(const _Float16* __restrict__ E,
                          const _Float16* __restrict__ Tmax,
                          const float* __restrict__ x,
                          const float* __restrict__ dict,
                          float* __restrict__ argout) {
  const int t = blockIdx.x;
  const int lane = threadIdx.x;            // 0..63
  float m0 = (float)Tmax[(size_t)lane * NTOK + t];
  float m1 = (float)Tmax[(size_t)(64 + lane) * NTOK + t];
  float mx = fmaxf(m0, m1);
  #pragma unroll
  for (int off = 32; off > 0; off >>= 1) mx = fmaxf(mx, __shfl_xor(mx, off, 64));

  __shared__ int cnt;
  __shared__ int cand[32];
  __shared__ double csc[32];
  if (lane == 0) cnt = 0;
  __syncthreads();

  if (mx > 0.0f) {
    float thr = 0.98f * mx;
    unsigned long long q0 = __ballot(m0 >= thr);
    unsigned long long q1 = __ballot(m1 >= thr);
    while (q0 | q1) {
      int tile;
      if (q0) { tile = __ffsll(q0) - 1; q0 &= q0 - 1; }
      else    { tile = 64 + __ffsll(q1) - 1; q1 &= q1 - 1; }
      const _Float16* ep = E + (size_t)t * NATOM + tile * 128;
      float e0 = (float)ep[lane], e1 = (float)ep[64 + lane];
      if (e0 >= thr) { int p = atomicAdd(&cnt, 1); if (p < 32) cand[p] = tile * 128 + lane; }
      if (e1 >= thr) { int p = atomicAdd(&cnt, 1); if (p < 32) cand[p] = tile * 128 + 64 + lane; }
    }
  }
  __syncthreads();
  int nc = min(cnt, 32);
  const float* xr = x + (size_t)t * DMODEL;
  for (int c = 0; c < nc; c++) {
    const float* dr = dict + (size_t)cand[c] * DMODEL;
    double a = 0.0;
    #pragma unroll
    for (int i = 0; i < 16; i++) {
      int d = lane + i * 64;
      a += (double)xr[d] * (double)dr[d];
    }
    #pragma unroll
    for (int off = 32; off > 0; off >>= 1) a += __shfl_down(a, off, 64);
    if (lane == 0) csc[c] = a;
  }
  __syncthreads();
  if (lane == 0) {
    int best = 0;                          // all-masked -> np.argmax of equal values = 0
    if (nc > 0) {
      double bs = -1e300;
      best = NATOM;
      for (int c = 0; c < nc; c++)
        if (csc[c] > bs || (csc[c] == bs && cand[c] < best)) { bs = csc[c]; best = cand[c]; }
    }
    argout[t] = (float)best;               // harness reads d_out as float32
  }
}

// ---------------- kernel 3: recon = (E @ dT^T) / l ----------------
// M64 x N256, grid (4,128)=512 blocks (2/CU), double-buffered staging (2x20KB).
__launch_bounds__(256, 2)
__global__ void recon_kernel(const _Float16* __restrict__ E,
                             const _Float16* __restrict__ DT,
                             const float* __restrict__ lsum,
                             float* __restrict__ out) {
  __shared__ _Float16 lds[20480];          // 2 x (As 64x32 = 2048 + Bs 256x32 = 8192)
  const int tid  = threadIdx.x;
  const int lane = tid & 63;
  const int wave = tid >> 6;               // n-offset = wave*64
  const int m0 = blockIdx.y * 64;          // token tile
  const int n0 = blockIdx.x * 256;         // d_model tile

  const int frow = lane & 15;
  const int fkc  = lane >> 4;

  f32x4 acc[4][4] = {};

  auto stage = [&](int k0, int b) {
    _Float16* As = lds + b * 10240;
    _Float16* Bs = As + 2048;
    {
      int L = tid;                         // 64 rows x 4 chunks
      int r = L >> 2, pc = L & 3;
      int c = pc ^ ((r >> 1) & 3);
      GLOAD_LDS16(E + (size_t)(m0 + r) * NATOM + k0 + c * 8, As + (size_t)L * 8);
    }
    #pragma unroll
    for (int i = 0; i < 4; i++) {
      int L = tid + i * 256;               // 256 rows x 4 chunks
      int r = L >> 2, pc = L & 3;
      int c = pc ^ ((r >> 1) & 3);
      GLOAD_LDS16(DT + (size_t)(n0 + r) * NATOM + k0 + c * 8, Bs + (size_t)L * 8);
    }
  };

  stage(0, 0);
  int cur = 0;
  for (int it = 0; it < NATOM / 32; ++it) {
    __syncthreads();                       // buf[cur] ready (loads issued 1 compute-phase ago)
    if (it + 1 < NATOM / 32) stage((it + 1) * 32, cur ^ 1);
    _Float16* As = lds + cur * 10240;
    _Float16* Bs = As + 2048;
    half8 af[4], bf[4];
    #pragma unroll
    for (int i = 0; i < 4; i++) {
      int ar = i * 16 + frow;
      int br = wave * 64 + i * 16 + frow;
      af[i] = *(const half8*)&As[ar * 32 + (fkc ^ ((ar >> 1) & 3)) * 8];
      bf[i] = *(const half8*)&Bs[br * 32 + (fkc ^ ((br >> 1) & 3)) * 8];
    }
    #pragma unroll
    for (int i = 0; i < 4; i++)
      #pragma unroll
      for (int j = 0; j < 4; j++)
        acc[i][j] = __builtin_amdgcn_mfma_f32_16x16x32_f16(af[i], bf[j], acc[i][j], 0, 0, 0);
    cur ^= 1;
  }

  const int cr = (lane >> 4) * 4;
  const int cc = lane & 15;
  #pragma unroll
  for (int i = 0; i < 4; i++) {
    #pragma unroll
    for (int r = 0; r < 4; r++) {
      int lr = i * 16 + cr + r;
      float sc = 1.0f / lsum[m0 + lr];
      #pragma unroll
      for (int j = 0; j < 4; j++) {
        int lc = wave * 64 + j * 16 + cc;
        out[(size_t)(m0 + lr) * DMODEL + (n0 + lc)] = acc[i][j][r] * sc;
      }
    }
  }
}

extern "C" void kernel_launch(void* const* d_in, const int* in_sizes, int n_in,
                              void* d_out, int out_size, void* d_ws, size_t ws_size,
                              hipStream_t stream) {
  const float* x    = (const float*)d_in[0];
  const float* dict = (const float*)d_in[1];
  const int*   mask = (const int*)d_in[2];
  float* recon  = (float*)d_out;
  float* argout = recon + (size_t)NTOK * DMODEL;

  // workspace layout (336 MB + 32 KB — proven size)
  char* w = (char*)d_ws;
  _Float16* Xh = (_Float16*)(w);                                 // 16 MB  [8192,1024]
  _Float16* Dh = (_Float16*)(w + (size_t)16  * 1024 * 1024);     // 32 MB  [16384,1024]
  _Float16* DT = (_Float16*)(w + (size_t)48  * 1024 * 1024);     // 32 MB  [1024,16384]
  _Float16* E  = (_Float16*)(w + (size_t)80  * 1024 * 1024);     // 256 MB [8192,16384]
  float*  lsum = (float*)  (w + (size_t)336 * 1024 * 1024);      // 32 KB
  // Tmax (2 MB fp16) borrows the front of d_out's recon region; scan_lite consumes it
  // before recon_kernel overwrites the region (stream-serialized).
  _Float16* Tmax = (_Float16*)d_out;                             // [128][8192]

  cvt_f32_f16<<<dim3(NTOK * DMODEL / 4 / 256), 256, 0, stream>>>(x, Xh, NTOK * DMODEL / 4);
  transpose_dict<<<dim3(NATOM / 64, DMODEL / 64), 256, 0, stream>>>(dict, Dh, DT);
  zero_lsum<<<dim3(NTOK / 256), 256, 0, stream>>>(lsum);
  score_kernel<<<dim3(NATOM / 128, NTOK / 128), 256, 0, stream>>>(Xh, Dh, mask, E, lsum, Tmax);
  scan_lite<<<dim3(NTOK), 64, 0, stream>>>(E, Tmax, x, dict, argout);
  recon_kernel<<<dim3(DMODEL / 256, NTOK / 64), 256, 0, stream>>>(E, DT, lsum, recon);
}